// Round 1
// baseline (380.606 us; speedup 1.0000x reference)
//
#include <hip/hip_runtime.h>

#define B_ 64
#define T_ 256
#define DF 32
#define L_ 128
#define FW 132   // feature row stride in floats (33 float4s) — bank stagger via j0
#define AW 34    // augmented matrix row stride (32 cols + y col + pad)

__global__ __launch_bounds__(256) void feat_kernel(
    const float* __restrict__ x,       // [B,T,32]
    const float* __restrict__ latent,  // [B,T,128]
    const float* __restrict__ kern,    // [32,128]
    const float* __restrict__ bias,    // [32,128]
    const float* __restrict__ beta,    // [T]
    float* __restrict__ out,           // mode0: ws[B,T,128] ; mode1: out[B,128]
    int mode)
{
    __shared__ __align__(16) float Fa[33 * FW];   // rows 0..31 = features, row 32 = latent
    __shared__ float A[32 * AW];                  // augmented [A | y]
    __shared__ float xs[DF];
    __shared__ float sv[DF];
    __shared__ float red[4];

    const int tid = threadIdx.x;
    const int bt  = blockIdx.x;       // b*T + t
    const int t   = bt & (T_ - 1);

    float w_t = 0.f;
    if (mode == 1) {
        // block-wide sum of |beta| (T_ == 256 == blockDim)
        float v = fabsf(beta[tid]);
        #pragma unroll
        for (int o = 32; o > 0; o >>= 1) v += __shfl_down(v, o);
        if ((tid & 63) == 0) red[tid >> 6] = v;
        __syncthreads();
        float S = red[0] + red[1] + red[2] + red[3];
        w_t = fabsf(beta[t]) / S;
    }

    if (tid < DF) xs[tid] = x[(size_t)bt * DF + tid];
    if (tid >= 64 && tid < 96) {      // latent row -> Fa row 32 (float4)
        int j = tid - 64;
        float4 lv = reinterpret_cast<const float4*>(latent)[(size_t)bt * 32 + j];
        *reinterpret_cast<float4*>(&Fa[32 * FW + j * 4]) = lv;
    }
    __syncthreads();

    // features: F[d][l] = relu(x[d]*K[d][l] + B[d][l]), float4 over l
    for (int idx = tid; idx < DF * 32; idx += 256) {
        int d = idx >> 5, j = idx & 31;
        float4 K4 = reinterpret_cast<const float4*>(kern)[idx];
        float4 B4 = reinterpret_cast<const float4*>(bias)[idx];
        float xv = xs[d];
        float4 f;
        f.x = fmaxf(fmaf(xv, K4.x, B4.x), 0.f);
        f.y = fmaxf(fmaf(xv, K4.y, B4.y), 0.f);
        f.z = fmaxf(fmaf(xv, K4.z, B4.z), 0.f);
        f.w = fmaxf(fmaf(xv, K4.w, B4.w), 0.f);
        *reinterpret_cast<float4*>(&Fa[d * FW + j * 4]) = f;
    }
    __syncthreads();

    // Gram pairs over 33 rows (row 32 = latent): d<=e, 561 pairs.
    // e<32 -> xtx entry; e==32 -> xty entry (col 32 of A).
    for (int p = tid; p < 561; p += 256) {
        int d = 0, start = 0;
        while (p >= start + (33 - d)) { start += 33 - d; ++d; }
        int e = d + (p - start);
        if (d == 32) continue;        // latent·latent, unused
        const float4* fd = reinterpret_cast<const float4*>(&Fa[d * FW]);
        const float4* fe = reinterpret_cast<const float4*>(&Fa[e * FW]);
        float a0 = 0, a1 = 0, a2 = 0, a3 = 0;
        int j0 = p & 31;              // lane-staggered start to spread banks
        #pragma unroll 8
        for (int jj = 0; jj < 32; ++jj) {
            int j = (jj + j0) & 31;
            float4 u = fd[j], v = fe[j];
            a0 = fmaf(u.x, v.x, a0);
            a1 = fmaf(u.y, v.y, a1);
            a2 = fmaf(u.z, v.z, a2);
            a3 = fmaf(u.w, v.w, a3);
        }
        float acc = (a0 + a1) + (a2 + a3);
        if (e < 32) { A[d * AW + e] = acc; A[e * AW + d] = acc; }
        else        { A[d * AW + 32] = acc; }
    }

    // Gauss-Jordan elimination (SPD, no pivoting), 32 threads own rows
    for (int k = 0; k < 32; ++k) {
        __syncthreads();
        if (tid < 32 && tid != k) {
            float f = A[tid * AW + k] / A[k * AW + k];
            for (int j = k + 1; j <= 32; ++j)
                A[tid * AW + j] = fmaf(-f, A[k * AW + j], A[tid * AW + j]);
        }
    }
    __syncthreads();
    if (tid < 32) sv[tid] = A[tid * AW + 32] / A[tid * AW + tid];
    __syncthreads();

    // o_hat[l] = sum_d s[d] * F[d][l]
    if (tid < L_) {
        float acc = 0.f;
        #pragma unroll
        for (int d = 0; d < DF; ++d) acc = fmaf(sv[d], Fa[d * FW + tid], acc);
        if (mode == 0) out[(size_t)bt * L_ + tid] = acc;
        else atomicAdd(&out[(size_t)(bt >> 8) * L_ + tid], acc * w_t);
    }
}

__global__ __launch_bounds__(256) void reduce_kernel(
    const float* __restrict__ ws,     // [B,T,128] o_hat (unscaled)
    const float* __restrict__ beta,   // [T]
    float* __restrict__ out)          // [B,128]
{
    __shared__ float wsh[T_];
    __shared__ float par[2][L_];
    int b = blockIdx.x, tid = threadIdx.x;
    if (tid < T_) wsh[tid] = fabsf(beta[tid]);
    __syncthreads();
    int l = tid & 127, h = tid >> 7;
    float acc = 0.f;
    for (int tt = 0; tt < 128; ++tt) {
        int t = h * 128 + tt;
        acc = fmaf(ws[((size_t)b * T_ + t) * L_ + l], wsh[t], acc);
    }
    par[h][l] = acc;
    __syncthreads();
    if (tid < L_) {
        float S = 0.f;
        for (int tt = 0; tt < T_; ++tt) S += wsh[tt];
        out[(size_t)b * L_ + tid] = (par[0][tid] + par[1][tid]) / S;
    }
}

extern "C" void kernel_launch(void* const* d_in, const int* in_sizes, int n_in,
                              void* d_out, int out_size, void* d_ws, size_t ws_size,
                              hipStream_t stream) {
    const float* x      = (const float*)d_in[0];
    const float* latent = (const float*)d_in[1];
    const float* kern   = (const float*)d_in[2];
    const float* bias   = (const float*)d_in[3];
    const float* beta   = (const float*)d_in[4];
    float* out = (float*)d_out;

    const size_t need = (size_t)B_ * T_ * L_ * sizeof(float);
    if (ws_size >= need) {
        float* ws = (float*)d_ws;
        feat_kernel<<<B_ * T_, 256, 0, stream>>>(x, latent, kern, bias, beta, ws, 0);
        reduce_kernel<<<B_, 256, 0, stream>>>(ws, beta, out);
    } else {
        hipMemsetAsync(d_out, 0, (size_t)out_size * sizeof(float), stream);
        feat_kernel<<<B_ * T_, 256, 0, stream>>>(x, latent, kern, bias, beta, out, 1);
    }
}

// Round 2
// 250.028 us; speedup vs baseline: 1.5223x; 1.5223x over previous
//
#include <hip/hip_runtime.h>

#define B_ 64
#define T_ 256
#define DF 32
#define L_ 128
#define FW4 33   // float4 stride of an F row (132 floats): +1 float4 pad for bank spread
#define AW 34    // augmented solve matrix row stride in floats

// One wave (64 threads) per (b,t) token. All barriers are single-wave (cheap).
__global__ __launch_bounds__(64) void feat_kernel(
    const float* __restrict__ x,       // [B,T,32]
    const float* __restrict__ latent,  // [B,T,128]
    const float* __restrict__ kern,    // [32,128]
    const float* __restrict__ bias,    // [32,128]
    const float* __restrict__ beta,    // [T]
    float* __restrict__ out,           // mode0: ws[B,T,128] ; mode1: out[B,128]
    int mode)
{
    __shared__ __align__(16) float Fs[33 * FW4 * 4];  // rows 0..31 features, row 32 latent
    __shared__ float As[DF * AW];                     // augmented [A | y]
    __shared__ float xs[DF];
    __shared__ float sv[DF];

    const int lane = threadIdx.x;      // 0..63
    const int bt   = blockIdx.x;

    float4* F4 = reinterpret_cast<float4*>(Fs);

    // ---- stage x (32 floats) and latent (row 32, 32 float4) ----
    if (lane < DF) xs[lane] = x[(size_t)bt * DF + lane];
    if (lane < 32) F4[32 * FW4 + lane] =
        reinterpret_cast<const float4*>(latent)[(size_t)bt * 32 + lane];
    __syncthreads();

    // ---- features: F[d][l] = relu(x[d]*K[d][l] + B[d][l]) ----
    {
        const float4* K4p = reinterpret_cast<const float4*>(kern);
        const float4* B4p = reinterpret_cast<const float4*>(bias);
        #pragma unroll
        for (int it = 0; it < 16; ++it) {
            int idx = lane + 64 * it;      // coalesced over 1024 float4s
            int d = idx >> 5, j = idx & 31;
            float4 K = K4p[idx], Bv = B4p[idx];
            float xv = xs[d];
            float4 f;
            f.x = fmaxf(fmaf(xv, K.x, Bv.x), 0.f);
            f.y = fmaxf(fmaf(xv, K.y, Bv.y), 0.f);
            f.z = fmaxf(fmaf(xv, K.z, Bv.z), 0.f);
            f.w = fmaxf(fmaf(xv, K.w, Bv.w), 0.f);
            F4[d * FW4 + j] = f;
        }
    }
    __syncthreads();

    // ---- Gram xtx: lane grid 8x8, 4x4 tile, interleaved rows d=lj+8r, e=li+8c ----
    // same-lj lanes broadcast fd; distinct rows interleave-by-1 -> distinct bank quads
    {
        const int li = lane & 7, lj = lane >> 3;
        float acc[4][4];
        #pragma unroll
        for (int r = 0; r < 4; ++r)
            #pragma unroll
            for (int c = 0; c < 4; ++c) acc[r][c] = 0.f;

        #pragma unroll 2
        for (int k = 0; k < 32; ++k) {
            float4 fd[4], fe[4];
            #pragma unroll
            for (int r = 0; r < 4; ++r) fd[r] = F4[(lj + 8 * r) * FW4 + k];
            #pragma unroll
            for (int c = 0; c < 4; ++c) fe[c] = F4[(li + 8 * c) * FW4 + k];
            #pragma unroll
            for (int r = 0; r < 4; ++r)
                #pragma unroll
                for (int c = 0; c < 4; ++c) {
                    acc[r][c] = fmaf(fd[r].x, fe[c].x, acc[r][c]);
                    acc[r][c] = fmaf(fd[r].y, fe[c].y, acc[r][c]);
                    acc[r][c] = fmaf(fd[r].z, fe[c].z, acc[r][c]);
                    acc[r][c] = fmaf(fd[r].w, fe[c].w, acc[r][c]);
                }
        }
        #pragma unroll
        for (int r = 0; r < 4; ++r)
            #pragma unroll
            for (int c = 0; c < 4; ++c)
                As[(lj + 8 * r) * AW + (li + 8 * c)] = acc[r][c];
    }

    // ---- xty -> As[:,32] : 64 lanes, k-halves, one cross-half shuffle ----
    {
        const int d = lane & 31, half = lane >> 5;
        float a0 = 0, a1 = 0, a2 = 0, a3 = 0;
        #pragma unroll
        for (int kk = 0; kk < 16; ++kk) {
            int k = half * 16 + kk;
            float4 fd = F4[d * FW4 + k];
            float4 lv = F4[32 * FW4 + k];
            a0 = fmaf(fd.x, lv.x, a0);
            a1 = fmaf(fd.y, lv.y, a1);
            a2 = fmaf(fd.z, lv.z, a2);
            a3 = fmaf(fd.w, lv.w, a3);
        }
        float ay = (a0 + a1) + (a2 + a3);
        ay += __shfl_down(ay, 32);
        if (half == 0) As[d * AW + 32] = ay;
    }
    __syncthreads();

    // ---- Gauss-Jordan (SPD, no pivot): row=lane&31, col-half=lane>>5 ----
    {
        const int row = lane & 31, half = lane >> 5;
        for (int k = 0; k < 32; ++k) {
            float piv = As[k * AW + k];
            float ip = __builtin_amdgcn_rcpf(piv);
            ip = ip * (2.0f - piv * ip);            // Newton refine
            float f = As[row * AW + k] * ip;
            if (row != k) {
                for (int j = k + 1 + half; j <= 32; j += 2)
                    As[row * AW + j] = fmaf(-f, As[k * AW + j], As[row * AW + j]);
            }
            __syncthreads();
        }
        if (lane < 32) sv[lane] = As[lane * AW + 32] / As[lane * AW + lane];
        __syncthreads();
    }

    // ---- o_hat[l] = sum_d s[d]*F[d][l], lane owns cols {2*lane, 2*lane+1} ----
    {
        const float2* F2 = reinterpret_cast<const float2*>(Fs);
        float2 oacc = make_float2(0.f, 0.f);
        #pragma unroll 4
        for (int d = 0; d < DF; ++d) {
            float2 fv = F2[d * (FW4 * 2) + lane];
            float s = sv[d];
            oacc.x = fmaf(s, fv.x, oacc.x);
            oacc.y = fmaf(s, fv.y, oacc.y);
        }
        if (mode == 0) {
            reinterpret_cast<float2*>(out)[(size_t)bt * 64 + lane] = oacc;
        } else {
            // fallback: beta-weighted atomic accumulate
            const int t = bt & (T_ - 1);
            float v = fabsf(beta[lane]) + fabsf(beta[lane + 64]) +
                      fabsf(beta[lane + 128]) + fabsf(beta[lane + 192]);
            #pragma unroll
            for (int o = 32; o > 0; o >>= 1) v += __shfl_down(v, o);
            float S = __shfl(v, 0);
            float w_t = fabsf(beta[t]) / S;
            float* op = &out[(size_t)(bt >> 8) * L_ + 2 * lane];
            atomicAdd(op + 0, oacc.x * w_t);
            atomicAdd(op + 1, oacc.y * w_t);
        }
    }
}

__global__ __launch_bounds__(256) void reduce_kernel(
    const float* __restrict__ ws,     // [B,T,128] o_hat (unscaled)
    const float* __restrict__ beta,   // [T]
    float* __restrict__ out)          // [B,128]
{
    __shared__ float wsh[T_];
    __shared__ float par[2][L_];
    int b = blockIdx.x, tid = threadIdx.x;
    if (tid < T_) wsh[tid] = fabsf(beta[tid]);
    __syncthreads();
    int l = tid & 127, h = tid >> 7;
    float acc = 0.f;
    for (int tt = 0; tt < 128; ++tt) {
        int t = h * 128 + tt;
        acc = fmaf(ws[((size_t)b * T_ + t) * L_ + l], wsh[t], acc);
    }
    par[h][l] = acc;
    __syncthreads();
    if (tid < L_) {
        float S = 0.f;
        for (int tt = 0; tt < T_; ++tt) S += wsh[tt];
        out[(size_t)b * L_ + tid] = (par[0][tid] + par[1][tid]) / S;
    }
}

extern "C" void kernel_launch(void* const* d_in, const int* in_sizes, int n_in,
                              void* d_out, int out_size, void* d_ws, size_t ws_size,
                              hipStream_t stream) {
    const float* x      = (const float*)d_in[0];
    const float* latent = (const float*)d_in[1];
    const float* kern   = (const float*)d_in[2];
    const float* bias   = (const float*)d_in[3];
    const float* beta   = (const float*)d_in[4];
    float* out = (float*)d_out;

    const size_t need = (size_t)B_ * T_ * L_ * sizeof(float);
    if (ws_size >= need) {
        float* ws = (float*)d_ws;
        feat_kernel<<<B_ * T_, 64, 0, stream>>>(x, latent, kern, bias, beta, ws, 0);
        reduce_kernel<<<B_, 256, 0, stream>>>(ws, beta, out);
    } else {
        hipMemsetAsync(d_out, 0, (size_t)out_size * sizeof(float), stream);
        feat_kernel<<<B_ * T_, 64, 0, stream>>>(x, latent, kern, bias, beta, out, 1);
    }
}

// Round 3
// 170.386 us; speedup vs baseline: 2.2338x; 1.4674x over previous
//
#include <hip/hip_runtime.h>

#define B_ 64
#define T_ 256
#define DF 32
#define L_ 128
#define AW 34   // solve-matrix row stride (32 + y + pad); stride 34 mod 32 = 2 -> 2-way max (free)

// One wave (64 threads) per (b,t) token. 8.5 KB LDS/block -> ~19 blocks/CU.
__global__ __launch_bounds__(64) void feat_kernel(
    const float* __restrict__ x,       // [B,T,32]
    const float* __restrict__ latent,  // [B,T,128]
    const float* __restrict__ kern,    // [32,128]
    const float* __restrict__ bias,    // [32,128]
    const float* __restrict__ beta,    // [T]
    float* __restrict__ out,           // mode0: ws[B,T,128] ; mode1: out[B,128]
    int mode)
{
    // F half-tile: 32 rows x 16 float4 (XOR-swizzled), 8192 B.
    // As (32x34 floats, 4352 B) + sv (128 B) alias it once F is dead.
    __shared__ __align__(16) char smem[8704];
    float4* F4 = reinterpret_cast<float4*>(smem);
    float*  As = reinterpret_cast<float*>(smem);
    float*  sv = reinterpret_cast<float*>(smem + 4352);

    const int lane = threadIdx.x;      // 0..63
    const int bt   = blockIdx.x;
    const int half = lane >> 5;
    const int l5   = lane & 31;
    const int li   = lane & 7;         // Gram col group
    const int lj   = lane >> 3;        // Gram row group

    const float4* kern4 = reinterpret_cast<const float4*>(kern);
    const float4* bias4 = reinterpret_cast<const float4*>(bias);
    const float4* lat4  = reinterpret_cast<const float4*>(latent) + (size_t)bt * 32;
    const float*  xp    = x + (size_t)bt * DF;

    float acc[4][4];
    #pragma unroll
    for (int r = 0; r < 4; ++r)
        #pragma unroll
        for (int c = 0; c < 4; ++c) acc[r][c] = 0.f;
    float ay = 0.f;

    // ---- two passes over the L dimension: f4-cols [0,16) then [16,32) ----
    #pragma unroll 1
    for (int p = 0; p < 2; ++p) {
        const int cb = p * 16;

        // features for this half: F[d][j] = relu(x[d]*K+B), swizzled store
        #pragma unroll
        for (int it = 0; it < 8; ++it) {
            int idx = lane + 64 * it;          // 0..511
            int d = idx >> 4, j = idx & 15;
            float4 K  = kern4[d * 32 + cb + j];
            float4 Bv = bias4[d * 32 + cb + j];
            float xv = xp[d];
            float4 f;
            f.x = fmaxf(fmaf(xv, K.x, Bv.x), 0.f);
            f.y = fmaxf(fmaf(xv, K.y, Bv.y), 0.f);
            f.z = fmaxf(fmaf(xv, K.z, Bv.z), 0.f);
            f.w = fmaxf(fmaf(xv, K.w, Bv.w), 0.f);
            F4[d * 16 + (j ^ (d & 7))] = f;
        }
        __syncthreads();

        // Gram partial: 8x8 lane grid, 4x4 interleaved row tile
        #pragma unroll 4
        for (int k = 0; k < 16; ++k) {
            float4 fd[4], fe[4];
            #pragma unroll
            for (int r = 0; r < 4; ++r) fd[r] = F4[(lj + 8 * r) * 16 + (k ^ lj)];
            #pragma unroll
            for (int c = 0; c < 4; ++c) fe[c] = F4[(li + 8 * c) * 16 + (k ^ li)];
            #pragma unroll
            for (int r = 0; r < 4; ++r)
                #pragma unroll
                for (int c = 0; c < 4; ++c) {
                    acc[r][c] = fmaf(fd[r].x, fe[c].x, acc[r][c]);
                    acc[r][c] = fmaf(fd[r].y, fe[c].y, acc[r][c]);
                    acc[r][c] = fmaf(fd[r].z, fe[c].z, acc[r][c]);
                    acc[r][c] = fmaf(fd[r].w, fe[c].w, acc[r][c]);
                }
        }

        // xty partial: row d = l5, k-halves split across wave halves
        #pragma unroll
        for (int kk = 0; kk < 8; ++kk) {
            int k = half * 8 + kk;
            float4 fv = F4[l5 * 16 + (k ^ (l5 & 7))];
            float4 yv = lat4[cb + k];
            ay = fmaf(fv.x, yv.x, ay);
            ay = fmaf(fv.y, yv.y, ay);
            ay = fmaf(fv.z, yv.z, ay);
            ay = fmaf(fv.w, yv.w, ay);
        }
        __syncthreads();   // all F reads done before overwrite / As alias
    }

    // ---- spill normal equations into LDS (aliases dead F region) ----
    #pragma unroll
    for (int r = 0; r < 4; ++r)
        #pragma unroll
        for (int c = 0; c < 4; ++c)
            As[(lj + 8 * r) * AW + (li + 8 * c)] = acc[r][c];
    ay += __shfl_down(ay, 32);
    if (half == 0) As[l5 * AW + 32] = ay;
    __syncthreads();

    // ---- Gauss-Jordan (SPD, no pivot): row = l5, col-half = half ----
    for (int k = 0; k < 32; ++k) {
        float piv = As[k * AW + k];
        float ip = __builtin_amdgcn_rcpf(piv);
        ip = ip * (2.0f - piv * ip);               // Newton refine
        float f = As[l5 * AW + k] * ip;
        if (l5 != k) {
            for (int j = k + 1 + half; j <= 32; j += 2)
                As[l5 * AW + j] = fmaf(-f, As[k * AW + j], As[l5 * AW + j]);
        }
        __syncthreads();
    }
    if (lane < 32) sv[lane] = As[lane * AW + 32] / As[lane * AW + lane];
    __syncthreads();

    // ---- o_hat: recompute F on the fly (K/B are L1-resident), f4-col = l5 ----
    {
        float4 o = make_float4(0.f, 0.f, 0.f, 0.f);
        #pragma unroll
        for (int dd = 0; dd < 16; ++dd) {
            int d = half * 16 + dd;
            float4 K  = kern4[d * 32 + l5];
            float4 Bv = bias4[d * 32 + l5];
            float xv = xp[d];
            float s  = sv[d];
            float fx = fmaxf(fmaf(xv, K.x, Bv.x), 0.f);
            float fy = fmaxf(fmaf(xv, K.y, Bv.y), 0.f);
            float fz = fmaxf(fmaf(xv, K.z, Bv.z), 0.f);
            float fw = fmaxf(fmaf(xv, K.w, Bv.w), 0.f);
            o.x = fmaf(s, fx, o.x);
            o.y = fmaf(s, fy, o.y);
            o.z = fmaf(s, fz, o.z);
            o.w = fmaf(s, fw, o.w);
        }
        o.x += __shfl_down(o.x, 32);
        o.y += __shfl_down(o.y, 32);
        o.z += __shfl_down(o.z, 32);
        o.w += __shfl_down(o.w, 32);

        if (mode == 0) {
            if (half == 0)
                reinterpret_cast<float4*>(out)[(size_t)bt * 32 + l5] = o;
        } else {
            const int t = bt & (T_ - 1);
            float v = fabsf(beta[lane]) + fabsf(beta[lane + 64]) +
                      fabsf(beta[lane + 128]) + fabsf(beta[lane + 192]);
            #pragma unroll
            for (int off = 32; off > 0; off >>= 1) v += __shfl_down(v, off);
            float S = __shfl(v, 0);
            float w_t = fabsf(beta[t]) / S;
            if (half == 0) {
                float* op = &out[(size_t)(bt >> 8) * L_ + 4 * l5];
                atomicAdd(op + 0, o.x * w_t);
                atomicAdd(op + 1, o.y * w_t);
                atomicAdd(op + 2, o.z * w_t);
                atomicAdd(op + 3, o.w * w_t);
            }
        }
    }
}

__global__ __launch_bounds__(256) void reduce_kernel(
    const float* __restrict__ ws,     // [B,T,128] o_hat (unscaled)
    const float* __restrict__ beta,   // [T]
    float* __restrict__ out)          // [B,128]
{
    __shared__ float wsh[T_];
    __shared__ __align__(16) float4 par[8][32];
    __shared__ float red[4];
    const int b = blockIdx.x, tid = threadIdx.x;

    float bv = fabsf(beta[tid]);
    wsh[tid] = bv;
    float v = bv;
    #pragma unroll
    for (int o = 32; o > 0; o >>= 1) v += __shfl_down(v, o);
    if ((tid & 63) == 0) red[tid >> 6] = v;
    __syncthreads();
    const float S = red[0] + red[1] + red[2] + red[3];

    const int c = tid & 31, g = tid >> 5;
    const float4* ws4 = reinterpret_cast<const float4*>(ws);
    float4 a = make_float4(0.f, 0.f, 0.f, 0.f);
    #pragma unroll 4
    for (int tt = 0; tt < 32; ++tt) {
        int t = g * 32 + tt;
        float w = wsh[t];
        float4 u = ws4[((size_t)b * T_ + t) * 32 + c];
        a.x = fmaf(u.x, w, a.x);
        a.y = fmaf(u.y, w, a.y);
        a.z = fmaf(u.z, w, a.z);
        a.w = fmaf(u.w, w, a.w);
    }
    par[g][c] = a;
    __syncthreads();
    if (tid < 32) {
        float4 s = par[0][tid];
        #pragma unroll
        for (int gg = 1; gg < 8; ++gg) {
            float4 u = par[gg][tid];
            s.x += u.x; s.y += u.y; s.z += u.z; s.w += u.w;
        }
        float inv = 1.0f / S;
        s.x *= inv; s.y *= inv; s.z *= inv; s.w *= inv;
        reinterpret_cast<float4*>(out)[b * 32 + tid] = s;
    }
}

extern "C" void kernel_launch(void* const* d_in, const int* in_sizes, int n_in,
                              void* d_out, int out_size, void* d_ws, size_t ws_size,
                              hipStream_t stream) {
    const float* x      = (const float*)d_in[0];
    const float* latent = (const float*)d_in[1];
    const float* kern   = (const float*)d_in[2];
    const float* bias   = (const float*)d_in[3];
    const float* beta   = (const float*)d_in[4];
    float* out = (float*)d_out;

    const size_t need = (size_t)B_ * T_ * L_ * sizeof(float);
    if (ws_size >= need) {
        float* ws = (float*)d_ws;
        feat_kernel<<<B_ * T_, 64, 0, stream>>>(x, latent, kern, bias, beta, ws, 0);
        reduce_kernel<<<B_, 256, 0, stream>>>(ws, beta, out);
    } else {
        hipMemsetAsync(d_out, 0, (size_t)out_size * sizeof(float), stream);
        feat_kernel<<<B_ * T_, 64, 0, stream>>>(x, latent, kern, bias, beta, out, 1);
    }
}

// Round 4
// 108.405 us; speedup vs baseline: 3.5110x; 1.5718x over previous
//
#include <hip/hip_runtime.h>

#define B_ 64
#define T_ 256
#define DF 32
#define L_ 128
#define AW 34   // solve-matrix row stride in floats (even -> b64-aligned row reads)

typedef float v2f __attribute__((ext_vector_type(2)));

__device__ __forceinline__ float readlane_f(float v, int l) {
    return __builtin_bit_cast(float, __builtin_amdgcn_readlane(__builtin_bit_cast(int, v), l));
}

// One wave (64 threads) per (b,t) token.
__global__ __launch_bounds__(64) void feat_kernel(
    const float* __restrict__ x,       // [B,T,32]
    const float* __restrict__ latent,  // [B,T,128]
    const float* __restrict__ kern,    // [32,128]
    const float* __restrict__ bias,    // [32,128]
    const float* __restrict__ beta,    // [T]
    float* __restrict__ out,           // mode0: ws[B,T,128] ; mode1: out[B,128]
    int mode)
{
    // F half-tile: 32 rows x 16 float4 (XOR-swizzled), 8192 B.
    // As (32x34 floats, 4352 B) + sv alias it once F is dead.
    __shared__ __align__(16) char smem[8192];
    float4* F4 = reinterpret_cast<float4*>(smem);
    float*  As = reinterpret_cast<float*>(smem);
    float*  sv = reinterpret_cast<float*>(smem + 4352);

    const int lane = threadIdx.x;      // 0..63
    const int bt   = blockIdx.x;
    const int half = lane >> 5;
    const int l5   = lane & 31;
    const int li   = lane & 7;         // Gram col group
    const int lj   = lane >> 3;        // Gram row group

    const float4* kern4 = reinterpret_cast<const float4*>(kern);
    const float4* bias4 = reinterpret_cast<const float4*>(bias);
    const float4* lat4  = reinterpret_cast<const float4*>(latent) + (size_t)bt * 32;
    const float*  xp    = x + (size_t)bt * DF;

    v2f acc2[4][4];
    #pragma unroll
    for (int r = 0; r < 4; ++r)
        #pragma unroll
        for (int c = 0; c < 4; ++c) acc2[r][c] = (v2f){0.f, 0.f};
    float ay = 0.f;

    // ---- two passes over L: f4-cols [0,16) then [16,32) ----
    #pragma unroll 1
    for (int p = 0; p < 2; ++p) {
        const int cb = p * 16;

        // features for this half: F[d][j] = relu(x[d]*K+B), swizzled store
        #pragma unroll
        for (int it = 0; it < 8; ++it) {
            int idx = lane + 64 * it;          // 0..511
            int d = idx >> 4, j = idx & 15;
            float4 K  = kern4[d * 32 + cb + j];
            float4 Bv = bias4[d * 32 + cb + j];
            float xv = xp[d];
            float4 f;
            f.x = fmaxf(fmaf(xv, K.x, Bv.x), 0.f);
            f.y = fmaxf(fmaf(xv, K.y, Bv.y), 0.f);
            f.z = fmaxf(fmaf(xv, K.z, Bv.z), 0.f);
            f.w = fmaxf(fmaf(xv, K.w, Bv.w), 0.f);
            F4[d * 16 + (j ^ (d & 7))] = f;
        }
        __syncthreads();

        // Gram partial: 8x8 lane grid, 4x4 interleaved row tile, packed-fp32 FMA
        #pragma unroll 4
        for (int k = 0; k < 16; ++k) {
            float4 fd[4], fe[4];
            #pragma unroll
            for (int r = 0; r < 4; ++r) fd[r] = F4[(lj + 8 * r) * 16 + (k ^ lj)];
            #pragma unroll
            for (int c = 0; c < 4; ++c) fe[c] = F4[(li + 8 * c) * 16 + (k ^ li)];
            #pragma unroll
            for (int r = 0; r < 4; ++r) {
                v2f dlo = reinterpret_cast<const v2f*>(&fd[r])[0];
                v2f dhi = reinterpret_cast<const v2f*>(&fd[r])[1];
                #pragma unroll
                for (int c = 0; c < 4; ++c) {
                    v2f elo = reinterpret_cast<const v2f*>(&fe[c])[0];
                    v2f ehi = reinterpret_cast<const v2f*>(&fe[c])[1];
                    asm("v_pk_fma_f32 %0, %1, %2, %0" : "+v"(acc2[r][c]) : "v"(dlo), "v"(elo));
                    asm("v_pk_fma_f32 %0, %1, %2, %0" : "+v"(acc2[r][c]) : "v"(dhi), "v"(ehi));
                }
            }
        }

        // xty partial: row d = l5, k-halves split across wave halves
        #pragma unroll
        for (int kk = 0; kk < 8; ++kk) {
            int k = half * 8 + kk;
            float4 fv = F4[l5 * 16 + (k ^ (l5 & 7))];
            float4 yv = lat4[cb + k];
            ay = fmaf(fv.x, yv.x, ay);
            ay = fmaf(fv.y, yv.y, ay);
            ay = fmaf(fv.z, yv.z, ay);
            ay = fmaf(fv.w, yv.w, ay);
        }
        __syncthreads();   // all F reads done before overwrite / As alias
    }

    // ---- spill normal equations into LDS (aliases dead F region) ----
    #pragma unroll
    for (int r = 0; r < 4; ++r)
        #pragma unroll
        for (int c = 0; c < 4; ++c)
            As[(lj + 8 * r) * AW + (li + 8 * c)] = acc2[r][c][0] + acc2[r][c][1];
    ay += __shfl_down(ay, 32);
    if (half == 0) As[l5 * AW + 32] = ay;
    __syncthreads();

    // ---- pull my row into registers (lanes 32..63 mirror rows 0..31) ----
    float A[33];
    #pragma unroll
    for (int jj = 0; jj < 16; ++jj) {
        v2f t = *reinterpret_cast<const v2f*>(&As[l5 * AW + 2 * jj]);
        A[2 * jj]     = t[0];
        A[2 * jj + 1] = t[1];
    }
    A[32] = As[l5 * AW + 32];

    // ---- register Gauss-Jordan (SPD, no pivot), fully unrolled, no barriers ----
    float dinv = 0.f;
    #pragma unroll
    for (int k = 0; k < 32; ++k) {
        float piv = readlane_f(A[k], k);
        float ip = __builtin_amdgcn_rcpf(piv);
        ip = ip * (2.0f - piv * ip);               // Newton refine
        const bool isk = (l5 == k);
        float fmul = isk ? 0.f : A[k] * ip;        // pivot row itself doesn't update
        dinv = isk ? ip : dinv;                    // capture my diagonal reciprocal
        #pragma unroll
        for (int j = k + 1; j <= 32; ++j) {
            float pkj = readlane_f(A[j], k);
            A[j] = fmaf(-fmul, pkj, A[j]);
        }
    }
    float s = A[32] * dinv;
    if (lane < 32) sv[lane] = s;
    __syncthreads();

    // ---- o_hat: recompute F on the fly (K/B are cache-resident), f4-col = l5 ----
    {
        float4 o = make_float4(0.f, 0.f, 0.f, 0.f);
        #pragma unroll
        for (int dd = 0; dd < 16; ++dd) {
            int d = half * 16 + dd;
            float4 K  = kern4[d * 32 + l5];
            float4 Bv = bias4[d * 32 + l5];
            float xv = xp[d];
            float sd = sv[d];
            float fx = fmaxf(fmaf(xv, K.x, Bv.x), 0.f);
            float fy = fmaxf(fmaf(xv, K.y, Bv.y), 0.f);
            float fz = fmaxf(fmaf(xv, K.z, Bv.z), 0.f);
            float fw = fmaxf(fmaf(xv, K.w, Bv.w), 0.f);
            o.x = fmaf(sd, fx, o.x);
            o.y = fmaf(sd, fy, o.y);
            o.z = fmaf(sd, fz, o.z);
            o.w = fmaf(sd, fw, o.w);
        }
        o.x += __shfl_down(o.x, 32);
        o.y += __shfl_down(o.y, 32);
        o.z += __shfl_down(o.z, 32);
        o.w += __shfl_down(o.w, 32);

        if (mode == 0) {
            if (half == 0)
                reinterpret_cast<float4*>(out)[(size_t)bt * 32 + l5] = o;
        } else {
            const int t = bt & (T_ - 1);
            float v = fabsf(beta[lane]) + fabsf(beta[lane + 64]) +
                      fabsf(beta[lane + 128]) + fabsf(beta[lane + 192]);
            #pragma unroll
            for (int off = 32; off > 0; off >>= 1) v += __shfl_down(v, off);
            float S = __shfl(v, 0);
            float w_t = fabsf(beta[t]) / S;
            if (half == 0) {
                float* op = &out[(size_t)(bt >> 8) * L_ + 4 * l5];
                atomicAdd(op + 0, o.x * w_t);
                atomicAdd(op + 1, o.y * w_t);
                atomicAdd(op + 2, o.z * w_t);
                atomicAdd(op + 3, o.w * w_t);
            }
        }
    }
}

__global__ __launch_bounds__(256) void reduce_kernel(
    const float* __restrict__ ws,     // [B,T,128] o_hat (unscaled)
    const float* __restrict__ beta,   // [T]
    float* __restrict__ out)          // [B,128]
{
    __shared__ float wsh[T_];
    __shared__ __align__(16) float4 par[8][32];
    __shared__ float red[4];
    const int b = blockIdx.x, tid = threadIdx.x;

    float bv = fabsf(beta[tid]);
    wsh[tid] = bv;
    float v = bv;
    #pragma unroll
    for (int o = 32; o > 0; o >>= 1) v += __shfl_down(v, o);
    if ((tid & 63) == 0) red[tid >> 6] = v;
    __syncthreads();
    const float S = red[0] + red[1] + red[2] + red[3];

    const int c = tid & 31, g = tid >> 5;
    const float4* ws4 = reinterpret_cast<const float4*>(ws);
    float4 a = make_float4(0.f, 0.f, 0.f, 0.f);
    #pragma unroll 4
    for (int tt = 0; tt < 32; ++tt) {
        int t = g * 32 + tt;
        float w = wsh[t];
        float4 u = ws4[((size_t)b * T_ + t) * 32 + c];
        a.x = fmaf(u.x, w, a.x);
        a.y = fmaf(u.y, w, a.y);
        a.z = fmaf(u.z, w, a.z);
        a.w = fmaf(u.w, w, a.w);
    }
    par[g][c] = a;
    __syncthreads();
    if (tid < 32) {
        float4 s = par[0][tid];
        #pragma unroll
        for (int gg = 1; gg < 8; ++gg) {
            float4 u = par[gg][tid];
            s.x += u.x; s.y += u.y; s.z += u.z; s.w += u.w;
        }
        float inv = 1.0f / S;
        s.x *= inv; s.y *= inv; s.z *= inv; s.w *= inv;
        reinterpret_cast<float4*>(out)[b * 32 + tid] = s;
    }
}

extern "C" void kernel_launch(void* const* d_in, const int* in_sizes, int n_in,
                              void* d_out, int out_size, void* d_ws, size_t ws_size,
                              hipStream_t stream) {
    const float* x      = (const float*)d_in[0];
    const float* latent = (const float*)d_in[1];
    const float* kern   = (const float*)d_in[2];
    const float* bias   = (const float*)d_in[3];
    const float* beta   = (const float*)d_in[4];
    float* out = (float*)d_out;

    const size_t need = (size_t)B_ * T_ * L_ * sizeof(float);
    if (ws_size >= need) {
        float* ws = (float*)d_ws;
        feat_kernel<<<B_ * T_, 64, 0, stream>>>(x, latent, kern, bias, beta, ws, 0);
        reduce_kernel<<<B_, 256, 0, stream>>>(ws, beta, out);
    } else {
        hipMemsetAsync(d_out, 0, (size_t)out_size * sizeof(float), stream);
        feat_kernel<<<B_ * T_, 64, 0, stream>>>(x, latent, kern, bias, beta, out, 1);
    }
}

// Round 6
// 99.276 us; speedup vs baseline: 3.8338x; 1.0920x over previous
//
#include <hip/hip_runtime.h>
#include <stdint.h>

#define B_ 64
#define T_ 256
#define DF 32
#define L_ 128
#define AW 34      // solve-matrix row stride in floats
#define SLICE 4608 // per-wave LDS slice: As 4352 + sv 128 + pad

typedef float f32x16 __attribute__((ext_vector_type(16)));
typedef short bf16x8 __attribute__((ext_vector_type(8)));

// wave-private barrier: drain LDS ops; sched_barrier stops hoisting (rule #18)
#define WAVE_SYNC() do { asm volatile("s_waitcnt lgkmcnt(0)" ::: "memory"); \
                         __builtin_amdgcn_sched_barrier(0); } while (0)

__device__ __forceinline__ float readlane_f(float v, int l) {
    return __builtin_bit_cast(float, __builtin_amdgcn_readlane(__builtin_bit_cast(int, v), l));
}
__device__ __forceinline__ uint32_t cvt_pk_bf16(float a, float b) {
    uint32_t r;
    asm("v_cvt_pk_bf16_f32 %0, %1, %2" : "=v"(r) : "v"(a), "v"(b));
    return r;   // lo16 = bf16(a), hi16 = bf16(b)
}
__device__ __forceinline__ float lo_f(uint32_t p) { return __builtin_bit_cast(float, p << 16); }
__device__ __forceinline__ float hi_f(uint32_t p) { return __builtin_bit_cast(float, p & 0xFFFF0000u); }

struct frag3 { bf16x8 h, m, l; };
union U8 { uint32_t u[4]; bf16x8 v; };

// 3-way bf16 split of 8 f32 values (two float4): f = h + m + l, residual ~2^-27
__device__ __forceinline__ frag3 split3(float4 a, float4 b) {
    uint32_t h0 = cvt_pk_bf16(a.x, a.y), h1 = cvt_pk_bf16(a.z, a.w);
    uint32_t h2 = cvt_pk_bf16(b.x, b.y), h3 = cvt_pk_bf16(b.z, b.w);
    float e0 = a.x - lo_f(h0), e1 = a.y - hi_f(h0);
    float e2 = a.z - lo_f(h1), e3 = a.w - hi_f(h1);
    float e4 = b.x - lo_f(h2), e5 = b.y - hi_f(h2);
    float e6 = b.z - lo_f(h3), e7 = b.w - hi_f(h3);
    uint32_t m0 = cvt_pk_bf16(e0, e1), m1 = cvt_pk_bf16(e2, e3);
    uint32_t m2 = cvt_pk_bf16(e4, e5), m3 = cvt_pk_bf16(e6, e7);
    float g0 = e0 - lo_f(m0), g1 = e1 - hi_f(m0);
    float g2 = e2 - lo_f(m1), g3 = e3 - hi_f(m1);
    float g4 = e4 - lo_f(m2), g5 = e5 - hi_f(m2);
    float g6 = e6 - lo_f(m3), g7 = e7 - hi_f(m3);
    uint32_t l0 = cvt_pk_bf16(g0, g1), l1 = cvt_pk_bf16(g2, g3);
    uint32_t l2 = cvt_pk_bf16(g4, g5), l3 = cvt_pk_bf16(g6, g7);
    U8 H, M, L;
    H.u[0] = h0; H.u[1] = h1; H.u[2] = h2; H.u[3] = h3;
    M.u[0] = m0; M.u[1] = m1; M.u[2] = m2; M.u[3] = m3;
    L.u[0] = l0; L.u[1] = l1; L.u[2] = l2; L.u[3] = l3;
    frag3 r; r.h = H.v; r.m = M.v; r.l = L.v; return r;
}

__device__ __forceinline__ f32x16 mfma32(bf16x8 a, bf16x8 b, f32x16 c) {
    return __builtin_amdgcn_mfma_f32_32x32x16_bf16(a, b, c, 0, 0, 0);
}

// One wave per (b,t) token; 4 independent waves per 256-thread block.
__global__ __launch_bounds__(256, 4) void feat_kernel(
    const float* __restrict__ x,       // [B,T,32]
    const float* __restrict__ latent,  // [B,T,128]
    const float* __restrict__ kern,    // [32,128]
    const float* __restrict__ bias,    // [32,128]
    const float* __restrict__ beta,    // [T]
    float* __restrict__ out,           // mode0: ws[B,T,128] ; mode1: out[B,128]
    int mode)
{
    __shared__ __align__(16) char smem[4 * SLICE];
    const int tid  = threadIdx.x;
    const int wid  = tid >> 6;
    const int lane = tid & 63;
    const int bt   = blockIdx.x * 4 + wid;

    float* As = reinterpret_cast<float*>(smem + wid * SLICE);
    float* sv = reinterpret_cast<float*>(smem + wid * SLICE + 4352);

    const int g  = lane >> 5;   // k-group (also wave half)
    const int r  = lane & 31;   // my feature row / solve row / o_hat column

    const float4* kern4 = reinterpret_cast<const float4*>(kern);
    const float4* bias4 = reinterpret_cast<const float4*>(bias);
    const float4* lat4  = reinterpret_cast<const float4*>(latent) + (size_t)bt * 32;
    const float*  xp    = x + (size_t)bt * DF;

    const float xr = xp[r];

    f32x16 Ga, Gb;
    #pragma unroll
    for (int i = 0; i < 16; ++i) { Ga[i] = 0.f; Gb[i] = 0.f; }
    float ay = 0.f;

    // ---- 8 k-steps of 16: build row-frag, MFMA Gram (3-split, 6 products), VALU xty ----
    #pragma unroll 2
    for (int ks = 0; ks < 8; ++ks) {
        const int idx = r * 32 + ks * 4 + g * 2;   // float4 index; k = ks*16 + g*8
        float4 Ka = kern4[idx],     Kb = kern4[idx + 1];
        float4 Ba = bias4[idx],     Bb = bias4[idx + 1];
        float4 fa, fb;
        fa.x = fmaxf(fmaf(xr, Ka.x, Ba.x), 0.f);
        fa.y = fmaxf(fmaf(xr, Ka.y, Ba.y), 0.f);
        fa.z = fmaxf(fmaf(xr, Ka.z, Ba.z), 0.f);
        fa.w = fmaxf(fmaf(xr, Ka.w, Ba.w), 0.f);
        fb.x = fmaxf(fmaf(xr, Kb.x, Bb.x), 0.f);
        fb.y = fmaxf(fmaf(xr, Kb.y, Bb.y), 0.f);
        fb.z = fmaxf(fmaf(xr, Kb.z, Bb.z), 0.f);
        fb.w = fmaxf(fmaf(xr, Kb.w, Bb.w), 0.f);

        // xty partial in f32 (exact path, no bf16 loss)
        float4 la = lat4[ks * 4 + g * 2], lb = lat4[ks * 4 + g * 2 + 1];
        ay = fmaf(fa.x, la.x, ay); ay = fmaf(fa.y, la.y, ay);
        ay = fmaf(fa.z, la.z, ay); ay = fmaf(fa.w, la.w, ay);
        ay = fmaf(fb.x, lb.x, ay); ay = fmaf(fb.y, lb.y, ay);
        ay = fmaf(fb.z, lb.z, ay); ay = fmaf(fb.w, lb.w, ay);

        frag3 F = split3(fa, fb);
        // G += F F^T : hh + hm + mh + hl + lh + mm  (two acc chains for ILP)
        Ga = mfma32(F.h, F.h, Ga);
        Gb = mfma32(F.h, F.m, Gb);
        Ga = mfma32(F.m, F.h, Ga);
        Gb = mfma32(F.h, F.l, Gb);
        Ga = mfma32(F.l, F.h, Ga);
        Gb = mfma32(F.m, F.m, Gb);
    }
    ay += __shfl_xor(ay, 32);   // combine the two k-halves -> full xty[r] in every lane

    // ---- spill G + xty into per-wave LDS solve matrix ----
    #pragma unroll
    for (int reg = 0; reg < 16; ++reg) {
        const int row = (reg & 3) + 8 * (reg >> 2) + 4 * g;  // m101 C-layout
        As[row * AW + r] = Ga[reg] + Gb[reg];
    }
    if (g == 0) As[r * AW + 32] = ay;
    WAVE_SYNC();

    // ---- pull my row into registers (lanes 32..63 mirror rows 0..31) ----
    float A[33];
    #pragma unroll
    for (int jj = 0; jj < 16; ++jj) {
        A[2 * jj]     = As[r * AW + 2 * jj];
        A[2 * jj + 1] = As[r * AW + 2 * jj + 1];
    }
    A[32] = As[r * AW + 32];

    // ---- register Gauss-Jordan (SPD, no pivot), fully unrolled, no barriers ----
    float dinv = 0.f;
    #pragma unroll
    for (int k = 0; k < 32; ++k) {
        float piv = readlane_f(A[k], k);
        float ip = __builtin_amdgcn_rcpf(piv);
        ip = ip * (2.0f - piv * ip);               // Newton refine
        const bool isk = (r == k);
        float fmul = isk ? 0.f : A[k] * ip;        // pivot row doesn't update
        dinv = isk ? ip : dinv;                    // capture my diagonal reciprocal
        #pragma unroll
        for (int j = k + 1; j <= 32; ++j) {
            float pkj = readlane_f(A[j], k);
            A[j] = fmaf(-fmul, pkj, A[j]);
        }
    }
    float s = A[32] * dinv;
    if (lane < 32) sv[lane] = s;
    WAVE_SYNC();

    // ---- o_hat: recompute F on the fly (K/B cache-resident), f4-col = r ----
    {
        float4 o = make_float4(0.f, 0.f, 0.f, 0.f);
        #pragma unroll
        for (int dd = 0; dd < 16; ++dd) {
            int d = g * 16 + dd;
            float4 K  = kern4[d * 32 + r];
            float4 Bv = bias4[d * 32 + r];
            float xv = xp[d];
            float sd = sv[d];
            float fx = fmaxf(fmaf(xv, K.x, Bv.x), 0.f);
            float fy = fmaxf(fmaf(xv, K.y, Bv.y), 0.f);
            float fz = fmaxf(fmaf(xv, K.z, Bv.z), 0.f);
            float fw = fmaxf(fmaf(xv, K.w, Bv.w), 0.f);
            o.x = fmaf(sd, fx, o.x);
            o.y = fmaf(sd, fy, o.y);
            o.z = fmaf(sd, fz, o.z);
            o.w = fmaf(sd, fw, o.w);
        }
        o.x += __shfl_down(o.x, 32);
        o.y += __shfl_down(o.y, 32);
        o.z += __shfl_down(o.z, 32);
        o.w += __shfl_down(o.w, 32);

        if (mode == 0) {
            if (g == 0)
                reinterpret_cast<float4*>(out)[(size_t)bt * 32 + r] = o;
        } else {
            const int t = bt & (T_ - 1);
            float v = fabsf(beta[lane]) + fabsf(beta[lane + 64]) +
                      fabsf(beta[lane + 128]) + fabsf(beta[lane + 192]);
            #pragma unroll
            for (int off = 32; off > 0; off >>= 1) v += __shfl_down(v, off);
            float S = __shfl(v, 0);
            float w_t = fabsf(beta[t]) / S;
            if (g == 0) {
                float* op = &out[(size_t)(bt >> 8) * L_ + 4 * r];
                atomicAdd(op + 0, o.x * w_t);
                atomicAdd(op + 1, o.y * w_t);
                atomicAdd(op + 2, o.z * w_t);
                atomicAdd(op + 3, o.w * w_t);
            }
        }
    }
}

__global__ __launch_bounds__(256) void reduce_kernel(
    const float* __restrict__ ws,     // [B,T,128] o_hat (unscaled)
    const float* __restrict__ beta,   // [T]
    float* __restrict__ out)          // [B,128]
{
    __shared__ float wsh[T_];
    __shared__ __align__(16) float4 par[8][32];
    __shared__ float red[4];
    const int b = blockIdx.x, tid = threadIdx.x;

    float bv = fabsf(beta[tid]);
    wsh[tid] = bv;
    float v = bv;
    #pragma unroll
    for (int o = 32; o > 0; o >>= 1) v += __shfl_down(v, o);
    if ((tid & 63) == 0) red[tid >> 6] = v;
    __syncthreads();
    const float S = red[0] + red[1] + red[2] + red[3];

    const int c = tid & 31, gg = tid >> 5;
    const float4* ws4 = reinterpret_cast<const float4*>(ws);
    float4 a = make_float4(0.f, 0.f, 0.f, 0.f);
    #pragma unroll 4
    for (int tt = 0; tt < 32; ++tt) {
        int t = gg * 32 + tt;
        float w = wsh[t];
        float4 u = ws4[((size_t)b * T_ + t) * 32 + c];
        a.x = fmaf(u.x, w, a.x);
        a.y = fmaf(u.y, w, a.y);
        a.z = fmaf(u.z, w, a.z);
        a.w = fmaf(u.w, w, a.w);
    }
    par[gg][c] = a;
    __syncthreads();
    if (tid < 32) {
        float4 s = par[0][tid];
        #pragma unroll
        for (int p = 1; p < 8; ++p) {
            float4 u = par[p][tid];
            s.x += u.x; s.y += u.y; s.z += u.z; s.w += u.w;
        }
        float inv = 1.0f / S;
        s.x *= inv; s.y *= inv; s.z *= inv; s.w *= inv;
        reinterpret_cast<float4*>(out)[b * 32 + tid] = s;
    }
}

extern "C" void kernel_launch(void* const* d_in, const int* in_sizes, int n_in,
                              void* d_out, int out_size, void* d_ws, size_t ws_size,
                              hipStream_t stream) {
    const float* x      = (const float*)d_in[0];
    const float* latent = (const float*)d_in[1];
    const float* kern   = (const float*)d_in[2];
    const float* bias   = (const float*)d_in[3];
    const float* beta   = (const float*)d_in[4];
    float* out = (float*)d_out;

    const size_t need = (size_t)B_ * T_ * L_ * sizeof(float);
    if (ws_size >= need) {
        float* ws = (float*)d_ws;
        feat_kernel<<<(B_ * T_) / 4, 256, 0, stream>>>(x, latent, kern, bias, beta, ws, 0);
        reduce_kernel<<<B_, 256, 0, stream>>>(ws, beta, out);
    } else {
        (void)hipMemsetAsync(d_out, 0, (size_t)out_size * sizeof(float), stream);
        feat_kernel<<<(B_ * T_) / 4, 256, 0, stream>>>(x, latent, kern, bias, beta, out, 1);
    }
}